// Round 1
// 358.879 us; speedup vs baseline: 1.0002x; 1.0002x over previous
//
#include <hip/hip_runtime.h>
#include <hip/hip_bf16.h>
#include <math.h>

#define CCH 192
#define EPS 1e-5f

typedef float vfloat4 __attribute__((ext_vector_type(4)));

__device__ __constant__ int d_LOWX[32] = {0,0,1,1,0,2,2,1,2,0,3,4,0,1,3,0,1,2,3,4,5,0,1,2,3,4,5,6,1,2,3,4};
__device__ __constant__ int d_LOWY[32] = {0,1,0,1,2,0,1,2,2,3,0,0,4,3,1,5,4,3,2,1,0,6,5,4,3,2,1,0,6,5,4,3};

// ---------------- K1: fused pre-pass, one launch, three block roles ----------------
//  blocks [0,3072):   unweighted adaptive pool  x -> xp[n][c][49]  (register accum, no LDS atomics)
//  blocks [3072,3216): pack wt[k*192+c] = w1d[c][k][1]
//  blocks [3216,3272): gate conv rows for n=0 -> partial[h][32]    (LDS-free, shuffle reduce)
__global__ __launch_bounds__(256) void fused_pre_kernel(
    const float* __restrict__ x, const float* __restrict__ w1d,
    const float* __restrict__ wg1,
    const float* __restrict__ bn2_g, const float* __restrict__ bn2_b,
    const float* __restrict__ bn2_m, const float* __restrict__ bn2_v,
    float* __restrict__ xp, float* __restrict__ wt, float* __restrict__ partial) {
  __shared__ float smem[4 * 49];       // 784 B: pool-role staging only
  const int b = blockIdx.x;
  const int t = threadIdx.x;
  if (b < 3072) {
    // ---- pool role: 4 waves, one channel per wave.
    // Per row-group g (8 rows = 112 float4): two coalesced 56-lane passes.
    // Lane l<56 has FIXED (r = l/14, wq = l%14); pass adds 4 rows.
    // acc[g] = cols [4wq,4wq+4) of rows {8g+r, 8g+r+4}.
    const int n = b / 48, c0 = (b % 48) * 4;
    const int wv = t >> 6, l = t & 63;
    const int c = c0 + wv;
    const bool act = l < 56;
    const int lidx = act ? l : 0;      // keep OOB lanes safe
    const vfloat4* xv = (const vfloat4*)(x + (size_t)(n * CCH + c) * 3136);
    float acc[7];
#pragma unroll
    for (int g = 0; g < 7; ++g) {
      vfloat4 v0 = xv[g * 112 + lidx];
      vfloat4 v1 = xv[g * 112 + 56 + lidx];
      float s = (v0.x + v0.y + v0.z + v0.w) + (v1.x + v1.y + v1.z + v1.w);
      acc[g] = act ? s : 0.f;
    }
#pragma unroll
    for (int g = 0; g < 7; ++g) {
      // pair lanes (wq even, wq odd) -> 8-col sum for rows {r, r+4}
      float a = acc[g] + __shfl_xor(acc[g], 1);
      // sum r with r+2 (lane +28), then r(0,1) pairs (lane +14)
      a += __shfl(a, l + 28);
      a += __shfl(a, l + 14);
      // valid at l = 2*cc, cc in [0,7): full 8x8 block sum for cell (g, cc)
      if (act && l < 14 && (l & 1) == 0)
        smem[wv * 49 + g * 7 + (l >> 1)] = a;
    }
    __syncthreads();
    if (t < 196) xp[((size_t)n * CCH + c0) * 49 + t] = smem[t] * (1.f / 64.f);
  } else if (b < 3216) {
    // ---- pack role
    const int i = (b - 3072) * 256 + t;           // < 36864
    const int cc = i / CCH, k = i - cc * CCH;
    wt[k * CCH + cc] = w1d[cc * (CCH * 3) + 3 * k + 1];
  } else {
    // ---- gate role (n=0 only): one h row per block; wave wv owns outputs [8wv,8wv+8)
    // over ALL 192 channels -> no cross-wave combine, no LDS.
    const int h = b - 3216;
    const int wv = t >> 6, w = t & 63;
    float acc[8];
#pragma unroll
    for (int o = 0; o < 8; ++o) acc[o] = 0.f;
    const float* xrow = x + h * 56;               // x[c*3136 + h*56 + w]
    for (int cc = 0; cc < CCH; ++cc) {
      float xvv = (w < 56) ? xrow[cc * 3136 + w] : 0.f;
#pragma unroll
      for (int o = 0; o < 8; ++o)
        acc[o] += xvv * wg1[(wv * 8 + o) * CCH + cc];  // uniform -> s_load
    }
#pragma unroll
    for (int o = 0; o < 8; ++o) {
      const int oo = wv * 8 + o;
      float sc = bn2_g[oo] * rsqrtf(bn2_v[oo] + EPS);
      float v = acc[o] * sc + (bn2_b[oo] - bn2_m[oo] * sc);
      v = (w < 56) ? fmaxf(v, 0.f) : 0.f;         // BN offset must not leak into pad lanes
#pragma unroll
      for (int s = 1; s < 64; s <<= 1) v += __shfl_xor(v, s);
      if (w == 0) partial[h * 32 + oo] = v;
    }
  }
}

// ---------------- K2: reduce -> xg0 -> param -> filt (1 block) ----------------
__global__ __launch_bounds__(256) void mid_kernel(
    const float* __restrict__ partial, const float* __restrict__ wg2,
    const float* __restrict__ bg2, const float* __restrict__ beta,
    float* __restrict__ filt) {
  __shared__ float gm[32];
  __shared__ float xg[32];
  __shared__ float param[33];
  __shared__ float Btab[7][7];
  const int t = threadIdx.x;
  if (t < 32) {
    float s = 0.f;
    for (int hh = 0; hh < 56; ++hh) s += partial[hh * 32 + t];
    gm[t] = s * (1.f / 3136.f);
  }
  if (t < 49) {
    int f = t / 7, tt = t % 7;
    float r = cosf(3.14159265358979323846f * (float)f * ((float)tt + 0.5f) / 7.f) * rsqrtf(7.f);
    Btab[f][tt] = (f == 0) ? r : r * sqrtf(2.f);
  }
  __syncthreads();
  if (t < 32) {
    float a = bg2[t];
    for (int k = 0; k < 32; ++k) a += gm[k] * wg2[t * 32 + k];
    xg[t] = fmaxf(tanhf(a), 0.f) + beta[0];
  }
  __syncthreads();
  if (t == 0) {
    float s = 0.f;
    for (int k = 0; k < 32; ++k) s += xg[k];
    float psum = 0.f;
    param[0] = 0.f;
    for (int i = 0; i < 31; ++i) {
      float p = rintf(xg[i] / s * (float)CCH);  // nearest-even, matches jnp.round
      param[i + 1] = p;
      psum += p;
    }
    param[32] = (float)CCH - psum;
  }
  __syncthreads();
  for (int c = t; c < CCH; c += 256) {
    int bi = -1;
    float cf = (float)c;
    for (int i = 0; i < 32; ++i)
      if (cf >= param[i] && cf < param[i + 1]) bi = i;  // last match wins
    int fx = (bi >= 0) ? d_LOWX[bi] : 0;
    int fy = (bi >= 0) ? d_LOWY[bi] : 0;
    for (int cell = 0; cell < 49; ++cell) {
      int a = cell / 7, bb = cell % 7;
      float v = (bi >= 0) ? Btab[fx][a] * Btab[fy][bb] : 0.f;
      filt[c * 49 + cell] = v;
    }
  }
}

// ---------------- K3: yvec = sum(xp*filt) -> GEMV -> BN1 -> ReLU -> scale ----------------
// grid 64 (n), block 256 (192 active)
__global__ __launch_bounds__(256) void gemv_scale_kernel(
    const float* __restrict__ xp, const float* __restrict__ filt,
    const float* __restrict__ wt, const float* __restrict__ b1d,
    const float* __restrict__ bn1_g, const float* __restrict__ bn1_b,
    const float* __restrict__ bn1_m, const float* __restrict__ bn1_v,
    float* __restrict__ scale) {
  __shared__ float yl[CCH];
  const int n = blockIdx.x, t = threadIdx.x;
  if (t < CCH) {
    const float* xc = xp + ((size_t)n * CCH + t) * 49;
    const float* fc = filt + t * 49;
    float s = 0.f;
#pragma unroll
    for (int cell = 0; cell < 49; ++cell) s += xc[cell] * fc[cell];
    yl[t] = s;
  }
  __syncthreads();
  if (t < CCH) {
    float acc = b1d[t];
#pragma unroll 4
    for (int k = 0; k < CCH; ++k) acc += yl[k] * wt[k * CCH + t];
    float sc = bn1_g[t] * rsqrtf(bn1_v[t] + EPS);
    float v = (acc - bn1_m[t]) * sc + bn1_b[t];
    scale[n * CCH + t] = 1.f + fmaxf(v, 0.f);
  }
}

// ---------------- K4: out = x * scale[n,c] ----------------
// x read is CACHED (L3-warm from fused_pre); out store stays nontemporal so the
// write-once output doesn't evict x from L3.
__global__ __launch_bounds__(256) void apply_kernel(
    const float* __restrict__ x, const float* __restrict__ scale,
    float* __restrict__ out) {
  const int f = blockIdx.x * 256 + threadIdx.x;   // float4 index < 9,633,792
  const int nc = f / 784;                          // 784 float4s per (n,c)
  const float s = scale[nc];
  vfloat4 v = ((const vfloat4*)x)[f];
  v *= s;
  __builtin_nontemporal_store(v, ((vfloat4*)out) + f);
}

extern "C" void kernel_launch(void* const* d_in, const int* in_sizes, int n_in,
                              void* d_out, int out_size, void* d_ws, size_t ws_size,
                              hipStream_t stream) {
  const float* x     = (const float*)d_in[0];
  const float* wg1   = (const float*)d_in[1];
  const float* bn2_g = (const float*)d_in[2];
  const float* bn2_b = (const float*)d_in[3];
  const float* bn2_m = (const float*)d_in[4];
  const float* bn2_v = (const float*)d_in[5];
  const float* wg2   = (const float*)d_in[6];
  const float* bg2   = (const float*)d_in[7];
  const float* beta  = (const float*)d_in[8];
  const float* w1d   = (const float*)d_in[9];
  const float* b1d   = (const float*)d_in[10];
  const float* bn1_g = (const float*)d_in[11];
  const float* bn1_b = (const float*)d_in[12];
  const float* bn1_m = (const float*)d_in[13];
  const float* bn1_v = (const float*)d_in[14];
  float* out = (float*)d_out;

  float* ws      = (float*)d_ws;
  float* partial = ws;                   // 56*32      = 1792
  float* filt    = partial + 1792;       // 192*49     = 9408
  float* wt      = filt + 9408;          // 192*192    = 36864
  float* xp      = wt + 36864;           // 64*192*49  = 602112
  float* scale   = xp + 602112;          // 64*192     = 12288

  fused_pre_kernel<<<3272, 256, 0, stream>>>(x, w1d, wg1, bn2_g, bn2_b, bn2_m, bn2_v,
                                             xp, wt, partial);
  mid_kernel<<<1, 256, 0, stream>>>(partial, wg2, bg2, beta, filt);
  gemv_scale_kernel<<<64, 256, 0, stream>>>(xp, filt, wt, b1d, bn1_g, bn1_b, bn1_m, bn1_v, scale);
  apply_kernel<<<37632, 256, 0, stream>>>(x, scale, out);
}

// Round 2
// 340.429 us; speedup vs baseline: 1.0544x; 1.0542x over previous
//
#include <hip/hip_runtime.h>
#include <hip/hip_bf16.h>
#include <math.h>

#define CCH 192
#define EPS 1e-5f

typedef float vfloat4 __attribute__((ext_vector_type(4)));

__device__ __constant__ int d_LOWX[32] = {0,0,1,1,0,2,2,1,2,0,3,4,0,1,3,0,1,2,3,4,5,0,1,2,3,4,5,6,1,2,3,4};
__device__ __constant__ int d_LOWY[32] = {0,1,0,1,2,0,1,2,2,3,0,0,4,3,1,5,4,3,2,1,0,6,5,4,3,2,1,0,6,5,4,3};

// ---------------- K1: fused pre-pass, one launch, three block roles ----------------
//  blocks [0,56):     gate conv rows for n=0 -> partial[h][32]  (FIRST so the latency-bound
//                     channel loop overlaps the pool phase instead of trailing it)
//  blocks [56,200):   pack wt[k*192+c] = w1d[c][k][1]
//  blocks [200,3272): unweighted adaptive pool  x -> xp[n][c][49] (register accum)
__global__ __launch_bounds__(256) void fused_pre_kernel(
    const float* __restrict__ x, const float* __restrict__ w1d,
    const float* __restrict__ wg1,
    const float* __restrict__ bn2_g, const float* __restrict__ bn2_b,
    const float* __restrict__ bn2_m, const float* __restrict__ bn2_v,
    float* __restrict__ xp, float* __restrict__ wt, float* __restrict__ partial) {
  __shared__ float smem[4 * 49];       // 784 B: pool-role staging only
  const int b = blockIdx.x;
  const int t = threadIdx.x;
  if (b >= 200) {
    // ---- pool role: 4 waves, one channel per wave.
    // Load phase fully separated from reduce phase: all 14 float4 loads issue
    // before any vmcnt wait (max memory-level parallelism per wave).
    const int pb = b - 200;
    const int n = pb / 48, c0 = (pb % 48) * 4;
    const int wv = t >> 6, l = t & 63;
    const int c = c0 + wv;
    const bool act = l < 56;
    const int lidx = act ? l : 0;      // keep OOB lanes safe
    const vfloat4* xv = (const vfloat4*)(x + (size_t)(n * CCH + c) * 3136);
    vfloat4 va[7], vb[7];
#pragma unroll
    for (int g = 0; g < 7; ++g) {
      va[g] = xv[g * 112 + lidx];
      vb[g] = xv[g * 112 + 56 + lidx];
    }
    float acc[7];
#pragma unroll
    for (int g = 0; g < 7; ++g) {
      float s = (va[g].x + va[g].y + va[g].z + va[g].w) +
                (vb[g].x + vb[g].y + vb[g].z + vb[g].w);
      acc[g] = act ? s : 0.f;
    }
#pragma unroll
    for (int g = 0; g < 7; ++g) {
      // pair lanes (wq even, wq odd) -> 8-col sum for rows {r, r+4}
      float a = acc[g] + __shfl_xor(acc[g], 1);
      a += __shfl(a, l + 28);          // r with r+2
      a += __shfl(a, l + 14);          // r(0,1) pairs
      if (act && l < 14 && (l & 1) == 0)
        smem[wv * 49 + g * 7 + (l >> 1)] = a;
    }
    __syncthreads();
    if (t < 196) xp[((size_t)n * CCH + c0) * 49 + t] = smem[t] * (1.f / 64.f);
  } else if (b >= 56) {
    // ---- pack role
    const int i = (b - 56) * 256 + t;             // < 36864
    const int cc = i / CCH, k = i - cc * CCH;
    wt[k * CCH + cc] = w1d[cc * (CCH * 3) + 3 * k + 1];
  } else {
    // ---- gate role (n=0 only): one h row per block; wave wv owns outputs [8wv,8wv+8)
    // over ALL 192 channels; channel loop pipelined 8-deep (8 independent loads in
    // flight before the FMA block consumes them).
    const int h = b;
    const int wv = t >> 6, w = t & 63;
    float acc[8];
#pragma unroll
    for (int o = 0; o < 8; ++o) acc[o] = 0.f;
    const float* xrow = x + h * 56;               // x[c*3136 + h*56 + w]
    for (int cc0 = 0; cc0 < CCH; cc0 += 8) {
      float xq[8];
#pragma unroll
      for (int j = 0; j < 8; ++j)
        xq[j] = (w < 56) ? xrow[(size_t)(cc0 + j) * 3136 + w] : 0.f;
#pragma unroll
      for (int j = 0; j < 8; ++j)
#pragma unroll
        for (int o = 0; o < 8; ++o)
          acc[o] += xq[j] * wg1[(wv * 8 + o) * CCH + cc0 + j];  // uniform -> s_load
    }
#pragma unroll
    for (int o = 0; o < 8; ++o) {
      const int oo = wv * 8 + o;
      float sc = bn2_g[oo] * rsqrtf(bn2_v[oo] + EPS);
      float v = acc[o] * sc + (bn2_b[oo] - bn2_m[oo] * sc);
      v = (w < 56) ? fmaxf(v, 0.f) : 0.f;         // BN offset must not leak into pad lanes
#pragma unroll
      for (int s = 1; s < 64; s <<= 1) v += __shfl_xor(v, s);
      if (w == 0) partial[h * 32 + oo] = v;
    }
  }
}

// ---------------- K2: reduce -> xg0 -> param -> filt (1 block) ----------------
__global__ __launch_bounds__(256) void mid_kernel(
    const float* __restrict__ partial, const float* __restrict__ wg2,
    const float* __restrict__ bg2, const float* __restrict__ beta,
    float* __restrict__ filt) {
  __shared__ float gm[32];
  __shared__ float xg[32];
  __shared__ float param[33];
  __shared__ float Btab[7][7];
  const int t = threadIdx.x;
  if (t < 32) {
    float s = 0.f;
    for (int hh = 0; hh < 56; ++hh) s += partial[hh * 32 + t];
    gm[t] = s * (1.f / 3136.f);
  }
  if (t < 49) {
    int f = t / 7, tt = t % 7;
    float r = cosf(3.14159265358979323846f * (float)f * ((float)tt + 0.5f) / 7.f) * rsqrtf(7.f);
    Btab[f][tt] = (f == 0) ? r : r * sqrtf(2.f);
  }
  __syncthreads();
  if (t < 32) {
    float a = bg2[t];
    for (int k = 0; k < 32; ++k) a += gm[k] * wg2[t * 32 + k];
    xg[t] = fmaxf(tanhf(a), 0.f) + beta[0];
  }
  __syncthreads();
  if (t == 0) {
    float s = 0.f;
    for (int k = 0; k < 32; ++k) s += xg[k];
    float psum = 0.f;
    param[0] = 0.f;
    for (int i = 0; i < 31; ++i) {
      float p = rintf(xg[i] / s * (float)CCH);  // nearest-even, matches jnp.round
      param[i + 1] = p;
      psum += p;
    }
    param[32] = (float)CCH - psum;
  }
  __syncthreads();
  for (int c = t; c < CCH; c += 256) {
    int bi = -1;
    float cf = (float)c;
    for (int i = 0; i < 32; ++i)
      if (cf >= param[i] && cf < param[i + 1]) bi = i;  // last match wins
    int fx = (bi >= 0) ? d_LOWX[bi] : 0;
    int fy = (bi >= 0) ? d_LOWY[bi] : 0;
    for (int cell = 0; cell < 49; ++cell) {
      int a = cell / 7, bb = cell % 7;
      float v = (bi >= 0) ? Btab[fx][a] * Btab[fy][bb] : 0.f;
      filt[c * 49 + cell] = v;
    }
  }
}

// ---------------- K3: yvec = sum(xp*filt) -> GEMV -> BN1 -> ReLU -> scale ----------------
// grid 64 (n), block 256 (192 active)
__global__ __launch_bounds__(256) void gemv_scale_kernel(
    const float* __restrict__ xp, const float* __restrict__ filt,
    const float* __restrict__ wt, const float* __restrict__ b1d,
    const float* __restrict__ bn1_g, const float* __restrict__ bn1_b,
    const float* __restrict__ bn1_m, const float* __restrict__ bn1_v,
    float* __restrict__ scale) {
  __shared__ float yl[CCH];
  const int n = blockIdx.x, t = threadIdx.x;
  if (t < CCH) {
    const float* xc = xp + ((size_t)n * CCH + t) * 49;
    const float* fc = filt + t * 49;
    float s = 0.f;
#pragma unroll
    for (int cell = 0; cell < 49; ++cell) s += xc[cell] * fc[cell];
    yl[t] = s;
  }
  __syncthreads();
  if (t < CCH) {
    float acc = b1d[t];
#pragma unroll 8
    for (int k = 0; k < CCH; ++k) acc += yl[k] * wt[k * CCH + t];
    float sc = bn1_g[t] * rsqrtf(bn1_v[t] + EPS);
    float v = (acc - bn1_m[t]) * sc + bn1_b[t];
    scale[n * CCH + t] = 1.f + fmaxf(v, 0.f);
  }
}

// ---------------- K4: out = x * scale[n,c] ----------------
// 8 float4 per thread (8 independent load/store pairs in flight), 4704 blocks.
// x read cached (L3-warm from fused_pre); out store nontemporal (write-once).
__global__ __launch_bounds__(256) void apply_kernel(
    const float* __restrict__ x, const float* __restrict__ scale,
    float* __restrict__ out) {
  const int base = blockIdx.x * 2048 + threadIdx.x;  // 4704*2048 = 9,633,792 float4s
  const vfloat4* xv = (const vfloat4*)x;
  vfloat4* ov = (vfloat4*)out;
#pragma unroll
  for (int k = 0; k < 8; ++k) {
    const int f = base + k * 256;
    const float s = scale[f / 784];                  // 784 float4s per (n,c)
    vfloat4 v = xv[f];
    v *= s;
    __builtin_nontemporal_store(v, ov + f);
  }
}

extern "C" void kernel_launch(void* const* d_in, const int* in_sizes, int n_in,
                              void* d_out, int out_size, void* d_ws, size_t ws_size,
                              hipStream_t stream) {
  const float* x     = (const float*)d_in[0];
  const float* wg1   = (const float*)d_in[1];
  const float* bn2_g = (const float*)d_in[2];
  const float* bn2_b = (const float*)d_in[3];
  const float* bn2_m = (const float*)d_in[4];
  const float* bn2_v = (const float*)d_in[5];
  const float* wg2   = (const float*)d_in[6];
  const float* bg2   = (const float*)d_in[7];
  const float* beta  = (const float*)d_in[8];
  const float* w1d   = (const float*)d_in[9];
  const float* b1d   = (const float*)d_in[10];
  const float* bn1_g = (const float*)d_in[11];
  const float* bn1_b = (const float*)d_in[12];
  const float* bn1_m = (const float*)d_in[13];
  const float* bn1_v = (const float*)d_in[14];
  float* out = (float*)d_out;

  float* ws      = (float*)d_ws;
  float* partial = ws;                   // 56*32      = 1792
  float* filt    = partial + 1792;       // 192*49     = 9408
  float* wt      = filt + 9408;          // 192*192    = 36864
  float* xp      = wt + 36864;           // 64*192*49  = 602112
  float* scale   = xp + 602112;          // 64*192     = 12288

  fused_pre_kernel<<<3272, 256, 0, stream>>>(x, w1d, wg1, bn2_g, bn2_b, bn2_m, bn2_v,
                                             xp, wt, partial);
  mid_kernel<<<1, 256, 0, stream>>>(partial, wg2, bg2, beta, filt);
  gemv_scale_kernel<<<64, 256, 0, stream>>>(xp, filt, wt, b1d, bn1_g, bn1_b, bn1_m, bn1_v, scale);
  apply_kernel<<<4704, 256, 0, stream>>>(x, scale, out);
}

// Round 3
// 340.060 us; speedup vs baseline: 1.0556x; 1.0011x over previous
//
#include <hip/hip_runtime.h>
#include <hip/hip_bf16.h>
#include <math.h>

#define CCH 192
#define EPS 1e-5f

typedef float vfloat4 __attribute__((ext_vector_type(4)));

__device__ __constant__ int d_LOWX[32] = {0,0,1,1,0,2,2,1,2,0,3,4,0,1,3,0,1,2,3,4,5,0,1,2,3,4,5,6,1,2,3,4};
__device__ __constant__ int d_LOWY[32] = {0,1,0,1,2,0,1,2,2,3,0,0,4,3,1,5,4,3,2,1,0,6,5,4,3,2,1,0,6,5,4,3};

// ---------------- K1: fused pre-pass, one launch, three block roles ----------------
//  blocks [0,56):     gate conv rows for n=0 -> partial[h][32]  (first: latency-bound loop
//                     overlaps the pool phase instead of trailing it)
//  blocks [56,200):   pack wt[k*192+c] = w1d[c][k][1]
//  blocks [200,3272): unweighted adaptive pool  x -> xp[n][c][49] (register accum)
__global__ __launch_bounds__(256) void fused_pre_kernel(
    const float* __restrict__ x, const float* __restrict__ w1d,
    const float* __restrict__ wg1,
    const float* __restrict__ bn2_g, const float* __restrict__ bn2_b,
    const float* __restrict__ bn2_m, const float* __restrict__ bn2_v,
    float* __restrict__ xp, float* __restrict__ wt, float* __restrict__ partial) {
  __shared__ float smem[4 * 49];       // 784 B: pool-role staging only
  const int b = blockIdx.x;
  const int t = threadIdx.x;
  if (b >= 200) {
    // ---- pool role: 4 waves, one channel per wave; all 14 float4 loads issue
    // before any vmcnt wait (max memory-level parallelism per wave).
    const int pb = b - 200;
    const int n = pb / 48, c0 = (pb % 48) * 4;
    const int wv = t >> 6, l = t & 63;
    const int c = c0 + wv;
    const bool act = l < 56;
    const int lidx = act ? l : 0;      // keep OOB lanes safe
    const vfloat4* xv = (const vfloat4*)(x + (size_t)(n * CCH + c) * 3136);
    vfloat4 va[7], vb[7];
#pragma unroll
    for (int g = 0; g < 7; ++g) {
      va[g] = xv[g * 112 + lidx];
      vb[g] = xv[g * 112 + 56 + lidx];
    }
    float acc[7];
#pragma unroll
    for (int g = 0; g < 7; ++g) {
      float s = (va[g].x + va[g].y + va[g].z + va[g].w) +
                (vb[g].x + vb[g].y + vb[g].z + vb[g].w);
      acc[g] = act ? s : 0.f;
    }
#pragma unroll
    for (int g = 0; g < 7; ++g) {
      // pair lanes (wq even, wq odd) -> 8-col sum for rows {r, r+4}
      float a = acc[g] + __shfl_xor(acc[g], 1);
      a += __shfl(a, l + 28);          // r with r+2
      a += __shfl(a, l + 14);          // r(0,1) pairs
      if (act && l < 14 && (l & 1) == 0)
        smem[wv * 49 + g * 7 + (l >> 1)] = a;
    }
    __syncthreads();
    if (t < 196) xp[((size_t)n * CCH + c0) * 49 + t] = smem[t] * (1.f / 64.f);
  } else if (b >= 56) {
    // ---- pack role
    const int i = (b - 56) * 256 + t;             // < 36864
    const int cc = i / CCH, k = i - cc * CCH;
    wt[k * CCH + cc] = w1d[cc * (CCH * 3) + 3 * k + 1];
  } else {
    // ---- gate role (n=0 only): one h row per block; wave wv owns outputs [8wv,8wv+8)
    // over ALL 192 channels; channel loop pipelined 8-deep.
    const int h = b;
    const int wv = t >> 6, w = t & 63;
    float acc[8];
#pragma unroll
    for (int o = 0; o < 8; ++o) acc[o] = 0.f;
    const float* xrow = x + h * 56;               // x[c*3136 + h*56 + w]
    for (int cc0 = 0; cc0 < CCH; cc0 += 8) {
      float xq[8];
#pragma unroll
      for (int j = 0; j < 8; ++j)
        xq[j] = (w < 56) ? xrow[(size_t)(cc0 + j) * 3136 + w] : 0.f;
#pragma unroll
      for (int j = 0; j < 8; ++j)
#pragma unroll
        for (int o = 0; o < 8; ++o)
          acc[o] += xq[j] * wg1[(wv * 8 + o) * CCH + cc0 + j];  // uniform -> s_load
    }
#pragma unroll
    for (int o = 0; o < 8; ++o) {
      const int oo = wv * 8 + o;
      float sc = bn2_g[oo] * rsqrtf(bn2_v[oo] + EPS);
      float v = acc[o] * sc + (bn2_b[oo] - bn2_m[oo] * sc);
      v = (w < 56) ? fmaxf(v, 0.f) : 0.f;         // BN offset must not leak into pad lanes
#pragma unroll
      for (int s = 1; s < 64; s <<= 1) v += __shfl_xor(v, s);
      if (w == 0) partial[h * 32 + oo] = v;
    }
  }
}

// ---------------- K2: merged mid+gemv: partial -> xg0 -> param -> filt(LDS) ----------------
//                  -> yvec -> GEMV -> BN1 -> ReLU -> scale.  grid 64 (n), block 256.
// The mid part is recomputed redundantly per block with IDENTICAL sequential arithmetic
// to the previously-passing version (param's rintf boundary must not move).
__global__ __launch_bounds__(256) void scale_kernel(
    const float* __restrict__ partial, const float* __restrict__ wg2,
    const float* __restrict__ bg2, const float* __restrict__ beta,
    const float* __restrict__ xp, const float* __restrict__ wt,
    const float* __restrict__ b1d,
    const float* __restrict__ bn1_g, const float* __restrict__ bn1_b,
    const float* __restrict__ bn1_m, const float* __restrict__ bn1_v,
    float* __restrict__ scale) {
  __shared__ float gm[32];
  __shared__ float xg[32];
  __shared__ float param[33];
  __shared__ float Btab[7][7];
  __shared__ float filt[CCH][49];   // 37.6 KB
  __shared__ float yl[CCH];
  const int n = blockIdx.x, t = threadIdx.x;
  if (t < 32) {
    float s = 0.f;
    for (int hh = 0; hh < 56; ++hh) s += partial[hh * 32 + t];  // sequential: bit-stable
    gm[t] = s * (1.f / 3136.f);
  }
  if (t < 49) {
    int f = t / 7, tt = t % 7;
    float r = cosf(3.14159265358979323846f * (float)f * ((float)tt + 0.5f) / 7.f) * rsqrtf(7.f);
    Btab[f][tt] = (f == 0) ? r : r * sqrtf(2.f);
  }
  __syncthreads();
  if (t < 32) {
    float a = bg2[t];
    for (int k = 0; k < 32; ++k) a += gm[k] * wg2[t * 32 + k];
    xg[t] = fmaxf(tanhf(a), 0.f) + beta[0];
  }
  __syncthreads();
  if (t == 0) {
    float s = 0.f;
    for (int k = 0; k < 32; ++k) s += xg[k];
    float psum = 0.f;
    param[0] = 0.f;
    for (int i = 0; i < 31; ++i) {
      float p = rintf(xg[i] / s * (float)CCH);  // nearest-even, matches jnp.round
      param[i + 1] = p;
      psum += p;
    }
    param[32] = (float)CCH - psum;
  }
  __syncthreads();
  if (t < CCH) {
    int bi = -1;
    float cf = (float)t;
    for (int i = 0; i < 32; ++i)
      if (cf >= param[i] && cf < param[i + 1]) bi = i;  // last match wins
    int fx = (bi >= 0) ? d_LOWX[bi] : 0;
    int fy = (bi >= 0) ? d_LOWY[bi] : 0;
    for (int cell = 0; cell < 49; ++cell) {
      int a = cell / 7, bb = cell % 7;
      filt[t][cell] = (bi >= 0) ? Btab[fx][a] * Btab[fy][bb] : 0.f;
    }
  }
  __syncthreads();
  if (t < CCH) {
    const float* xc = xp + ((size_t)n * CCH + t) * 49;
    float s = 0.f;
#pragma unroll
    for (int cell = 0; cell < 49; ++cell) s += xc[cell] * filt[t][cell];
    yl[t] = s;
  }
  __syncthreads();
  if (t < CCH) {
    float acc = b1d[t];
#pragma unroll 8
    for (int k = 0; k < CCH; ++k) acc += yl[k] * wt[k * CCH + t];
    float sc = bn1_g[t] * rsqrtf(bn1_v[t] + EPS);
    float v = (acc - bn1_m[t]) * sc + bn1_b[t];
    scale[n * CCH + t] = 1.f + fmaxf(v, 0.f);
  }
}

// ---------------- K3: out = x * scale[n,c] ----------------
// Plain cached float4 load + store (the m13-verified 6.29 TB/s copy pattern).
// Nontemporal store removed: it took a slow path (~3.5 TB/s) and the L3-residency
// argument is void — the harness's 616 MB poison fills evict x every iteration anyway.
__global__ __launch_bounds__(256) void apply_kernel(
    const float* __restrict__ x, const float* __restrict__ scale,
    float* __restrict__ out) {
  const int base = blockIdx.x * 2048 + threadIdx.x;  // 4704*2048 = 9,633,792 float4s
  const vfloat4* __restrict__ xv = (const vfloat4*)x;
  vfloat4* __restrict__ ov = (vfloat4*)out;
#pragma unroll
  for (int k = 0; k < 8; ++k) {
    const int f = base + k * 256;
    const float s = scale[f / 784];                  // 784 float4s per (n,c)
    vfloat4 v = xv[f];
    ov[f] = v * s;
  }
}

extern "C" void kernel_launch(void* const* d_in, const int* in_sizes, int n_in,
                              void* d_out, int out_size, void* d_ws, size_t ws_size,
                              hipStream_t stream) {
  const float* x     = (const float*)d_in[0];
  const float* wg1   = (const float*)d_in[1];
  const float* bn2_g = (const float*)d_in[2];
  const float* bn2_b = (const float*)d_in[3];
  const float* bn2_m = (const float*)d_in[4];
  const float* bn2_v = (const float*)d_in[5];
  const float* wg2   = (const float*)d_in[6];
  const float* bg2   = (const float*)d_in[7];
  const float* beta  = (const float*)d_in[8];
  const float* w1d   = (const float*)d_in[9];
  const float* b1d   = (const float*)d_in[10];
  const float* bn1_g = (const float*)d_in[11];
  const float* bn1_b = (const float*)d_in[12];
  const float* bn1_m = (const float*)d_in[13];
  const float* bn1_v = (const float*)d_in[14];
  float* out = (float*)d_out;

  float* ws      = (float*)d_ws;
  float* partial = ws;                   // 56*32      = 1792
  float* filt    = partial + 1792;       // (unused slot kept for layout stability)
  float* wt      = filt + 9408;          // 192*192    = 36864
  float* xp      = wt + 36864;           // 64*192*49  = 602112
  float* scale   = xp + 602112;          // 64*192     = 12288

  fused_pre_kernel<<<3272, 256, 0, stream>>>(x, w1d, wg1, bn2_g, bn2_b, bn2_m, bn2_v,
                                             xp, wt, partial);
  scale_kernel<<<64, 256, 0, stream>>>(partial, wg2, bg2, beta, xp, wt, b1d,
                                       bn1_g, bn1_b, bn1_m, bn1_v, scale);
  apply_kernel<<<4704, 256, 0, stream>>>(x, scale, out);
}